// Round 2
// baseline (363.372 us; speedup 1.0000x reference)
//
#include <hip/hip_runtime.h>

// ---------------------------------------------------------------------------
// WindowAttention fused kernel for MI355X (gfx950). FP32 I/O per reference:
//   x         [2048][49][256] f32      mask   [64][49][49] f32
//   qkv_w     [256][768] f32           qkv_b  [768] f32
//   proj_w    [256][256] f32           proj_b [256] f32
//   bias_table[169][8] f32             rel_index [2401] i32
//   out       [2048][49][256] f32
// Internals: bf16 MFMA (16x16x32), fp32 accumulate, exp2-domain softmax.
// ---------------------------------------------------------------------------

typedef __attribute__((ext_vector_type(8))) short v8s;   // 8 x bf16 (4 VGPRs)
typedef __attribute__((ext_vector_type(4))) float v4f;   // MFMA accumulator

__device__ __forceinline__ unsigned short f2bf(float f) {   // RNE f32->bf16
    union { float f; unsigned int i; } v; v.f = f;
    unsigned int x = v.i;
    return (unsigned short)((x + 0x7fffu + ((x >> 16) & 1u)) >> 16);
}

#define NW1 196608              // W1f elements (48 tiles * 8 ksteps * 64 lanes * 8)
#define NW2 65536               // W2f elements (16 tiles * 8 ksteps * 64 lanes * 8)
#define NB1 768                 // B1v elements
#define NCB 1605632             // CBf elements (64*8*49*64), fp32
#define QSCALE_LOG2E 0.25503487f   // (1/sqrt(32)) * log2(e)
#define LOG2E 1.4426950408889634f

// ---------------------------------------------------------------------------
// Preprocessing: fragment-linear bf16 weights + fp32 combined bias/mask.
// W1f[((T*8+s)*64+l)*8+j] = qkv_w[s*32+(l>>4)*8+j][origcol(T*16+(l&15))]
//   (head-grouped cols: head h -> q0..31,k0..31,v0..31; q pre-scaled)
// CBf[w][h][i][c] = (bias[h][i][c] + mask[w][i][c]) * log2e; c>=49 -> -1e30
// ---------------------------------------------------------------------------
__global__ void wattn_preproc(const float* __restrict__ qkv_w,
                              const float* __restrict__ qkv_b,
                              const float* __restrict__ proj_w,
                              const float* __restrict__ bias_table,
                              const float* __restrict__ mask,
                              const int* __restrict__ rel_index,
                              unsigned short* __restrict__ W1f,
                              unsigned short* __restrict__ W2f,
                              float* __restrict__ B1v,
                              float* __restrict__ CBf)
{
    const int idx = blockIdx.x * 256 + threadIdx.x;
    if (idx < NW1) {
        const int j = idx & 7, l = (idx >> 3) & 63, s = (idx >> 9) & 7, T = idx >> 12;
        const int k = s * 32 + (l >> 4) * 8 + j;
        const int n = T * 16 + (l & 15);
        const int hh = n / 96, sub = n % 96;
        const int col = (sub < 32) ? (hh * 32 + sub)
                      : (sub < 64) ? (256 + hh * 32 + (sub - 32))
                                   : (512 + hh * 32 + (sub - 64));
        float v = qkv_w[k * 768 + col];
        if (sub < 32) v *= QSCALE_LOG2E;
        W1f[idx] = f2bf(v);
    } else if (idx < NW1 + NW2) {
        const int t = idx - NW1;
        const int j = t & 7, l = (t >> 3) & 63, s = (t >> 9) & 7, T = t >> 12;
        const int k = s * 32 + (l >> 4) * 8 + j;
        const int n = T * 16 + (l & 15);
        W2f[t] = f2bf(proj_w[k * 256 + n]);
    } else if (idx < NW1 + NW2 + NB1) {
        const int n = idx - NW1 - NW2;
        const int hh = n / 96, sub = n % 96;
        const int col = (sub < 32) ? (hh * 32 + sub)
                      : (sub < 64) ? (256 + hh * 32 + (sub - 32))
                                   : (512 + hh * 32 + (sub - 64));
        float v = qkv_b[col];
        if (sub < 32) v *= QSCALE_LOG2E;
        B1v[n] = v;
    } else {
        const int t = idx - (NW1 + NW2 + NB1);
        if (t < NCB) {
            const int c = t & 63;
            const int rr = t >> 6;
            const int r = rr % 49;
            const int q2 = rr / 49;
            const int hh = q2 & 7;
            const int w = q2 >> 3;
            float v;
            if (c < 49) {
                const int ri = rel_index[r * 49 + c];
                v = (bias_table[ri * 8 + hh] + mask[(w * 49 + r) * 49 + c]) * LOG2E;
            } else {
                v = -1e30f;
            }
            CBf[t] = v;
        }
    }
}

// ---------------------------------------------------------------------------
// Main fused kernel: one block (4 waves) per window.
// ---------------------------------------------------------------------------
__global__ __launch_bounds__(256, 2)
void wattn_main(const float* __restrict__ x,
                const unsigned short* __restrict__ W1f,
                const float* __restrict__ B1v,
                const float* __restrict__ CB,
                const unsigned short* __restrict__ W2f,
                const float* __restrict__ proj_b,
                float* __restrict__ out)
{
    // LDS total = 13328+3920+3920+4608+7056+25872 = 58704 B (2 blocks/CU)
    __shared__ __align__(16) unsigned short xs[49 * 136];  // x chunk bf16 [row][c0+0..127]
    __shared__ __align__(16) unsigned short qs[49 * 40];   // q  [token][d]
    __shared__ __align__(16) unsigned short ks[49 * 40];   // k  [token][d]
    __shared__ __align__(16) unsigned short Vs[32 * 72];   // v^T[d][token], cols 49..63 zeroed
    __shared__ __align__(16) unsigned short Ps[49 * 72];   // P  [query][key]
    __shared__ __align__(16) unsigned short Os[49 * 264];  // attn out [token][256]

    const int tid  = threadIdx.x;
    const int wave = tid >> 6;
    const int lane = tid & 63;
    const int quad = lane >> 4;
    const int l15  = lane & 15;
    const int b    = blockIdx.x;
    const int widx = b & 63;
    const float* xw = x + (long)b * 49 * 256;
    const v4f zero4 = {0.0f, 0.0f, 0.0f, 0.0f};

    // Zero Vs pad columns once (tokens 49..63; 0*garbage in PV could be NaN).
    for (int i = tid; i < 32 * 15; i += 256) { const int d = i / 15, c = 49 + i % 15; Vs[d * 72 + c] = 0; }

    // A-frag row bases (clamped pad rows)
    int arow[4];
    #pragma unroll
    for (int mt = 0; mt < 4; ++mt) {
        int m = mt * 16 + l15; if (m > 48) m = 48;
        arow[mt] = m * 136 + quad * 8;
    }

    // ---- two GEMM phases; wave w owns head (p*4 + w): 6 n-tiles x 4 m-tiles ----
    #pragma unroll 1
    for (int p = 0; p < 2; ++p) {
        v4f acc[6][4];
        #pragma unroll
        for (int i = 0; i < 6; ++i)
            #pragma unroll
            for (int mt = 0; mt < 4; ++mt) acc[i][mt] = zero4;

        const int T0 = p * 24 + wave * 6;
        const unsigned short* bb = W1f + T0 * 4096 + lane * 8;

        #pragma unroll 1
        for (int ch = 0; ch < 2; ++ch) {
            __syncthreads();   // previous consumers of xs done
            // stage x[:, ch*128 .. +128) -> bf16 LDS (coalesced float4 loads)
            for (int i = tid; i < 1568; i += 256) {
                const int r = i >> 5, cq = i & 31;
                const float4 v = *reinterpret_cast<const float4*>(xw + r * 256 + ch * 128 + cq * 4);
                ushort4 o;
                o.x = f2bf(v.x); o.y = f2bf(v.y); o.z = f2bf(v.z); o.w = f2bf(v.w);
                *reinterpret_cast<ushort4*>(&xs[r * 136 + cq * 4]) = o;
            }
            __syncthreads();
            #pragma unroll
            for (int s = 0; s < 4; ++s) {
                v8s afr[4];
                #pragma unroll
                for (int mt = 0; mt < 4; ++mt)
                    afr[mt] = *reinterpret_cast<const v8s*>(&xs[arow[mt] + s * 32]);
                v8s bfr[6];
                #pragma unroll
                for (int i = 0; i < 6; ++i)
                    bfr[i] = *reinterpret_cast<const v8s*>(bb + i * 4096 + (ch * 4 + s) * 512);
                #pragma unroll
                for (int i = 0; i < 6; ++i)
                    #pragma unroll
                    for (int mt = 0; mt < 4; ++mt)
                        acc[i][mt] = __builtin_amdgcn_mfma_f32_16x16x32_bf16(afr[mt], bfr[i], acc[i][mt], 0, 0, 0);
            }
        }
        // qkv bias
        #pragma unroll
        for (int i = 0; i < 6; ++i) {
            const float bv = B1v[(T0 + i) * 16 + l15];
            #pragma unroll
            for (int mt = 0; mt < 4; ++mt) {
                acc[i][mt].x += bv; acc[i][mt].y += bv; acc[i][mt].z += bv; acc[i][mt].w += bv;
            }
        }

        // ---- per-head attention ----
        for (int hh = 0; hh < 4; ++hh) {
            __syncthreads();   // protect qs/ks/Vs against previous head's readers
            if (wave == hh) {
                #pragma unroll
                for (int i = 0; i < 6; ++i) {
                    #pragma unroll
                    for (int mt = 0; mt < 4; ++mt) {
                        const int m0 = mt * 16 + quad * 4;
                        float vv[4] = {acc[i][mt].x, acc[i][mt].y, acc[i][mt].z, acc[i][mt].w};
                        if (i < 2) {
                            const int c = i * 16 + l15;
                            #pragma unroll
                            for (int r = 0; r < 4; ++r)
                                if (m0 + r < 49) qs[(m0 + r) * 40 + c] = f2bf(vv[r]);
                        } else if (i < 4) {
                            const int c = (i - 2) * 16 + l15;
                            #pragma unroll
                            for (int r = 0; r < 4; ++r)
                                if (m0 + r < 49) ks[(m0 + r) * 40 + c] = f2bf(vv[r]);
                        } else {
                            const int d = (i - 4) * 16 + l15;
                            if (mt < 3) {
                                ushort4 pk;
                                pk.x = f2bf(vv[0]); pk.y = f2bf(vv[1]);
                                pk.z = f2bf(vv[2]); pk.w = f2bf(vv[3]);
                                *reinterpret_cast<ushort4*>(&Vs[d * 72 + m0]) = pk;
                            } else if (quad == 0) {
                                Vs[d * 72 + 48] = f2bf(vv[0]);
                            }
                        }
                    }
                }
            }
            __syncthreads();

            const int h = p * 4 + hh;

            // QK^T (wave = query m-tile; pad rows clamped to 48)
            int aqr = wave * 16 + l15; if (aqr > 48) aqr = 48;
            const v8s aq = *reinterpret_cast<const v8s*>(&qs[aqr * 40 + quad * 8]);
            v4f sacc[4];
            #pragma unroll
            for (int nt = 0; nt < 4; ++nt) {
                int bkr = nt * 16 + l15; if (bkr > 48) bkr = 48;
                const v8s bk = *reinterpret_cast<const v8s*>(&ks[bkr * 40 + quad * 8]);
                sacc[nt] = __builtin_amdgcn_mfma_f32_16x16x32_bf16(aq, bk, zero4, 0, 0, 0);
            }

            // in-register softmax (exp2 domain; scale & log2e pre-folded)
            const float* cbb = CB + (((long)widx * 8 + h) * 49) * 64;
            float pout[4][4];
            #pragma unroll
            for (int r = 0; r < 4; ++r) {
                const int m = wave * 16 + quad * 4 + r;
                const int mc = m > 48 ? 48 : m;
                float s0 = sacc[0][r] + cbb[mc * 64 + l15];
                float s1 = sacc[1][r] + cbb[mc * 64 + 16 + l15];
                float s2 = sacc[2][r] + cbb[mc * 64 + 32 + l15];
                float s3 = sacc[3][r] + cbb[mc * 64 + 48 + l15];
                float mx = fmaxf(fmaxf(s0, s1), fmaxf(s2, s3));
                #pragma unroll
                for (int off = 1; off < 16; off <<= 1) mx = fmaxf(mx, __shfl_xor(mx, off, 16));
                const float e0 = __builtin_exp2f(s0 - mx);
                const float e1 = __builtin_exp2f(s1 - mx);
                const float e2 = __builtin_exp2f(s2 - mx);
                const float e3 = __builtin_exp2f(s3 - mx);
                float sm = (e0 + e1) + (e2 + e3);
                #pragma unroll
                for (int off = 1; off < 16; off <<= 1) sm += __shfl_xor(sm, off, 16);
                const float rs = __builtin_amdgcn_rcpf(sm);
                pout[r][0] = e0 * rs; pout[r][1] = e1 * rs;
                pout[r][2] = e2 * rs; pout[r][3] = e3 * rs;
            }
            #pragma unroll
            for (int r = 0; r < 4; ++r) {
                const int m = wave * 16 + quad * 4 + r;
                if (m < 49) {
                    #pragma unroll
                    for (int nt = 0; nt < 4; ++nt)
                        Ps[m * 72 + nt * 16 + l15] = f2bf(pout[r][nt]);
                }
            }
            __syncthreads();

            // P @ V  (pad key tokens have P==0 and Vs pad cols are zeroed)
            int mrc = wave * 16 + l15; if (mrc > 48) mrc = 48;
            v4f oacc[2] = {zero4, zero4};
            #pragma unroll
            for (int kt = 0; kt < 2; ++kt) {
                const v8s ap = *reinterpret_cast<const v8s*>(&Ps[mrc * 72 + kt * 32 + quad * 8]);
                #pragma unroll
                for (int n2 = 0; n2 < 2; ++n2) {
                    const v8s bv = *reinterpret_cast<const v8s*>(&Vs[(n2 * 16 + l15) * 72 + kt * 32 + quad * 8]);
                    oacc[n2] = __builtin_amdgcn_mfma_f32_16x16x32_bf16(ap, bv, oacc[n2], 0, 0, 0);
                }
            }
            #pragma unroll
            for (int n2 = 0; n2 < 2; ++n2) {
                const int c = h * 32 + n2 * 16 + l15;
                #pragma unroll
                for (int r = 0; r < 4; ++r) {
                    const int m = wave * 16 + quad * 4 + r;
                    if (m < 49) Os[m * 264 + c] = f2bf(oacc[n2][r]);
                }
            }
        } // hh
    } // p

    __syncthreads();

    // ---- projection: Os[49(->64)][256] @ proj_w -> out (fp32) ----
    v4f pacc[4][4];
    #pragma unroll
    for (int i = 0; i < 4; ++i)
        #pragma unroll
        for (int mt = 0; mt < 4; ++mt) pacc[i][mt] = zero4;

    int orow[4];
    #pragma unroll
    for (int mt = 0; mt < 4; ++mt) {
        int m = mt * 16 + l15; if (m > 48) m = 48;
        orow[mt] = m * 264 + quad * 8;
    }
    const unsigned short* wb = W2f + (wave * 4) * 4096 + lane * 8;

    #pragma unroll
    for (int s = 0; s < 8; ++s) {
        v8s afr[4];
        #pragma unroll
        for (int mt = 0; mt < 4; ++mt)
            afr[mt] = *reinterpret_cast<const v8s*>(&Os[orow[mt] + s * 32]);
        #pragma unroll
        for (int i = 0; i < 4; ++i) {
            const v8s bfp = *reinterpret_cast<const v8s*>(wb + i * 4096 + s * 512);
            #pragma unroll
            for (int mt = 0; mt < 4; ++mt)
                pacc[i][mt] = __builtin_amdgcn_mfma_f32_16x16x32_bf16(afr[mt], bfp, pacc[i][mt], 0, 0, 0);
        }
    }

    #pragma unroll
    for (int i = 0; i < 4; ++i) {
        const int c = (wave * 4 + i) * 16 + l15;
        const float pb = proj_b[c];
        #pragma unroll
        for (int mt = 0; mt < 4; ++mt) {
            #pragma unroll
            for (int r = 0; r < 4; ++r) {
                const int m = mt * 16 + quad * 4 + r;
                if (m < 49) out[((long)b * 49 + m) * 256 + c] = pacc[i][mt][r] + pb;
            }
        }
    }
}

// ---------------------------------------------------------------------------
extern "C" void kernel_launch(void* const* d_in, const int* in_sizes, int n_in,
                              void* d_out, int out_size, void* d_ws, size_t ws_size,
                              hipStream_t stream)
{
    const float* x          = (const float*)d_in[0];
    const float* mask       = (const float*)d_in[1];
    const float* qkv_w      = (const float*)d_in[2];
    const float* qkv_b      = (const float*)d_in[3];
    const float* proj_w     = (const float*)d_in[4];
    const float* proj_b     = (const float*)d_in[5];
    const float* bias_table = (const float*)d_in[6];
    const int*   rel_index  = (const int*)d_in[7];
    float* out = (float*)d_out;

    char* ws = (char*)d_ws;
    unsigned short* W1f = (unsigned short*)(ws);             // 393216 B
    unsigned short* W2f = (unsigned short*)(ws + 393216);    // 131072 B
    float*          B1v = (float*)(ws + 524288);             //   3072 B
    float*          CBf = (float*)(ws + 527360);             // 6422528 B (total ~6.95 MB)

    // 196608 + 65536 + 768 + 1605632 = 1868544 = 7299 * 256 exactly
    wattn_preproc<<<7299, 256, 0, stream>>>(qkv_w, qkv_b, proj_w, bias_table, mask,
                                            rel_index, W1f, W2f, B1v, CBf);
    wattn_main<<<2048, 256, 0, stream>>>(x, W1f, B1v, CBf, W2f, proj_b, out);
}